// Round 1
// 883.734 us; speedup vs baseline: 1.0381x; 1.0381x over previous
//
#include <hip/hip_runtime.h>

#define EPS 1e-5f
#define D4 32  // 128 dims = 32 float4s per row

typedef float __attribute__((ext_vector_type(4))) f32x4;

// Pass 1: per-segment sum and sum-of-squares per feature dim.
// grid = (blocksPerSeg, B), block = 256.
// Thread t: c4 = t&31 (float4 column), rg = t>>5 (row slot, 8 rows/iter).
// 2-way row unroll: two independent 16B loads in flight per wave.
__global__ __launch_bounds__(256) void pin_stats_kernel(
    const float* __restrict__ x, const int* __restrict__ seqlen,
    float* __restrict__ gsum, float* __restrict__ gsq) {
    const int b = blockIdx.y;
    const int start = seqlen[b];
    const int rows = seqlen[b + 1] - start;
    const int c4 = threadIdx.x & 31;
    const int rg = threadIdx.x >> 5;

    f32x4 sum = 0.f;
    f32x4 sq  = 0.f;
    const f32x4* xp = (const f32x4*)x + (size_t)start * D4;
    const int rstride = gridDim.x * 8;
    const size_t pstep = (size_t)rstride * D4;

    int r = blockIdx.x * 8 + rg;
    const f32x4* p = xp + (size_t)r * D4 + c4;
    // normal (cached) loads: we WANT x to fill L3 so pass 2 hits on the tail
    for (; r + rstride < rows; r += 2 * rstride, p += 2 * pstep) {
        f32x4 v0 = p[0];
        f32x4 v1 = p[pstep];
        sum += v0; sq += v0 * v0;
        sum += v1; sq += v1 * v1;
    }
    if (r < rows) {
        f32x4 v = p[0];
        sum += v; sq += v * v;
    }

    __shared__ f32x4 ssum[256];
    __shared__ f32x4 ssq[256];
    ssum[threadIdx.x] = sum;
    ssq[threadIdx.x]  = sq;
    __syncthreads();

    if (threadIdx.x < 32) {
        f32x4 ts = ssum[threadIdx.x];
        f32x4 tq = ssq[threadIdx.x];
        #pragma unroll
        for (int g = 1; g < 8; ++g) {
            ts += ssum[g * 32 + threadIdx.x];
            tq += ssq[g * 32 + threadIdx.x];
        }
        float* gs = gsum + b * 128 + threadIdx.x * 4;
        float* gq = gsq  + b * 128 + threadIdx.x * 4;
        atomicAdd(gs + 0, ts.x); atomicAdd(gs + 1, ts.y);
        atomicAdd(gs + 2, ts.z); atomicAdd(gs + 3, ts.w);
        atomicAdd(gq + 0, tq.x); atomicAdd(gq + 1, tq.y);
        atomicAdd(gq + 2, tq.z); atomicAdd(gq + 3, tq.w);
    }
}

// Pass 2: out = x * scale + shift.
// Non-temporal loads for x (dead after read) and non-temporal stores for out
// (never read) so the output stream doesn't evict the L3-resident tail of x.
__global__ __launch_bounds__(256) void pin_norm_kernel(
    const float* __restrict__ x, const int* __restrict__ seqlen,
    const float* __restrict__ gsum, const float* __restrict__ gsq,
    const float* __restrict__ weight, const float* __restrict__ bias,
    float* __restrict__ out) {
    const int b = blockIdx.y;
    const int start = seqlen[b];
    const int rows = seqlen[b + 1] - start;
    const int c4 = threadIdx.x & 31;
    const int rg = threadIdx.x >> 5;
    const int d = c4 * 4;

    const float inv_n = 1.0f / fmaxf((float)rows, 1.0f);
    f32x4 s  = *(const f32x4*)(gsum + b * 128 + d);
    f32x4 q  = *(const f32x4*)(gsq  + b * 128 + d);
    f32x4 w  = *(const f32x4*)(weight + d);
    f32x4 bi = *(const f32x4*)(bias + d);

    f32x4 m   = s * inv_n;
    f32x4 var = q * inv_n - m * m;
    f32x4 is;
    is.x = rsqrtf(var.x + EPS);
    is.y = rsqrtf(var.y + EPS);
    is.z = rsqrtf(var.z + EPS);
    is.w = rsqrtf(var.w + EPS);
    f32x4 scale = w * is;
    f32x4 shift = bi - m * scale;

    const f32x4* xp = (const f32x4*)x + (size_t)start * D4;
    f32x4* op = (f32x4*)out + (size_t)start * D4;
    const int rstride = gridDim.x * 8;
    const size_t pstep = (size_t)rstride * D4;

    int r = blockIdx.x * 8 + rg;
    size_t idx = (size_t)r * D4 + c4;
    for (; r + rstride < rows; r += 2 * rstride, idx += 2 * pstep) {
        f32x4 v0 = __builtin_nontemporal_load(xp + idx);
        f32x4 v1 = __builtin_nontemporal_load(xp + idx + pstep);
        f32x4 o0 = v0 * scale + shift;
        f32x4 o1 = v1 * scale + shift;
        __builtin_nontemporal_store(o0, op + idx);
        __builtin_nontemporal_store(o1, op + idx + pstep);
    }
    if (r < rows) {
        f32x4 v = __builtin_nontemporal_load(xp + idx);
        __builtin_nontemporal_store(v * scale + shift, op + idx);
    }
}

extern "C" void kernel_launch(void* const* d_in, const int* in_sizes, int n_in,
                              void* d_out, int out_size, void* d_ws, size_t ws_size,
                              hipStream_t stream) {
    const float* x      = (const float*)d_in[0];
    const int*   seqlen = (const int*)d_in[1];
    const float* weight = (const float*)d_in[2];
    const float* bias   = (const float*)d_in[3];
    float* out = (float*)d_out;

    const int B = in_sizes[1] - 1;            // 16
    float* gsum = (float*)d_ws;               // [B][128]
    float* gsq  = gsum + (size_t)B * 128;     // [B][128]

    // Workspace is poisoned to 0xAA before every launch — zero the accumulators.
    hipMemsetAsync(d_ws, 0, (size_t)B * 128 * 2 * sizeof(float), stream);

    dim3 block(256);
    dim3 grid1(128, B);   // 2048 blocks, ~61 row-iters each (2-way unrolled)
    pin_stats_kernel<<<grid1, block, 0, stream>>>(x, seqlen, gsum, gsq);

    dim3 grid2(128, B);   // 2048 blocks
    pin_norm_kernel<<<grid2, block, 0, stream>>>(x, seqlen, gsum, gsq, weight, bias, out);
}